// Round 6
// baseline (508.683 us; speedup 1.0000x reference)
//
#include <hip/hip_runtime.h>

typedef unsigned short u16;
typedef unsigned int u32;
typedef unsigned char u8;
typedef int v8i __attribute__((ext_vector_type(8)));
typedef int v4i __attribute__((ext_vector_type(4)));
typedef float v16f __attribute__((ext_vector_type(16)));

#define INV_SQRT32 0.17677669529663688f

// ---------------------------------------------------------------------------
// Stage 1: per-32-group FWHT (Sylvester Hadamard) + MXFP4 quantize.
// Output PRE-TILED (tile = 128 rows x 128 k):
//   data chunk16 (row, kb): tile = (row>>7)*ntk + (kb>>2)
//        byte = tile*8192 + (kb&3)*2048 + (row&127)*16
//   scale byte (row, kb):   tile*512 + (row&127)*4 + (kb&3)
// UNCHANGED from rounds 4/5.
// ---------------------------------------------------------------------------
__global__ __launch_bounds__(256) void rotquant4_kernel(
    const float* __restrict__ T, u8* __restrict__ Q4, u8* __restrict__ S,
    int ngroups, int gpr /* K/32 */, int ntk /* K/128 */)
{
    int g = blockIdx.x * 256 + threadIdx.x;
    if (g >= ngroups) return;

    int row = g / gpr;
    int kb  = g - row * gpr;

    const float4* src = (const float4*)(T + (size_t)g * 32);
    float v[32];
#pragma unroll
    for (int i = 0; i < 8; ++i) {
        float4 t = src[i];
        v[i*4+0] = t.x; v[i*4+1] = t.y; v[i*4+2] = t.z; v[i*4+3] = t.w;
    }

#pragma unroll
    for (int s = 1; s < 32; s <<= 1) {
#pragma unroll
        for (int i = 0; i < 32; ++i) {
            if (!(i & s)) {
                float a = v[i], b = v[i | s];
                v[i] = a + b;
                v[i | s] = a - b;
            }
        }
    }

    float amax = 0.f;
#pragma unroll
    for (int i = 0; i < 32; ++i) {
        v[i] *= INV_SQRT32;
        amax = fmaxf(amax, fabsf(v[i]));
    }

    u32 ab = __float_as_uint(amax);
    int be = (int)(ab >> 23);
    u32 w[4] = {0u, 0u, 0u, 0u};
    u8 sbyte = 0;
    if (be >= 3) {
        sbyte = (u8)(be - 2);               // E8M0 of 2^(be-129)
        float iscale = __uint_as_float((u32)(256 - be) << 23); // 2^(129-be)
#pragma unroll
        for (int i = 0; i < 32; ++i) {
            float a = v[i] * iscale;        // exact
            float m = fminf(fabsf(a), 6.0f);
            int c = (m < 0.25f) ? 0 :
                    (m < 0.75f) ? 1 :
                    (m < 1.25f) ? 2 :
                    (m < 1.75f) ? 3 :
                    (m < 2.5f)  ? 4 :
                    (m < 3.5f)  ? 5 :
                    (m < 5.0f)  ? 6 : 7;
            c |= (int)((__float_as_uint(a) >> 28) & 8u);
            w[i >> 3] |= (u32)c << (4 * (i & 7));
        }
    }

    size_t tile = (size_t)(row >> 7) * (size_t)ntk + (size_t)(kb >> 2);
    uint4 p; p.x = w[0]; p.y = w[1]; p.z = w[2]; p.w = w[3];
    *(uint4*)(Q4 + tile * 8192 + (size_t)(kb & 3) * 2048
              + (size_t)(row & 127) * 16) = p;
    S[tile * 512 + (size_t)(row & 127) * 4 + (kb & 3)] = sbyte;
}

// ---------------------------------------------------------------------------
// Stage 2: C = deq(A) * deq(B)^T + bias via MX-scaled FP4 MFMA.
// BM=256, BN=256, BK=128. 8 waves (2Mx4N), per-wave 128x64 (4x2 reg-block,
// 16 MFMA/K-tile/wave). 8-phase-style schedule: 4 phases/K-tile, each
// {ds_read bundle || stage-issue} -> barrier -> lgkmcnt(0) -> setprio(1)
// + 4 MFMA -> setprio(0) -> barrier. Triple-buffered LDS, loads staged
// 2 tiles ahead, boundary s_waitcnt vmcnt(5) (counted, never 0 mid-loop).
// LDS per buffer (34816 B):
//   A [half2][slot4][row128][16B] @0      (16 KB)
//   B [half2][slot4][row128][16B] @16384  (16 KB)
//   A scales [row256][4B]         @32768  (1 KB)
//   B scales [row256][4B]         @33792  (1 KB)
// ---------------------------------------------------------------------------
__device__ __forceinline__ void gload16(const void* g, void* l)
{
    __builtin_amdgcn_global_load_lds(
        (__attribute__((address_space(1))) void*)g,
        (__attribute__((address_space(3))) void*)l, 16, 0, 0);
}
__device__ __forceinline__ void gload4(const void* g, void* l)
{
    __builtin_amdgcn_global_load_lds(
        (__attribute__((address_space(1))) void*)g,
        (__attribute__((address_space(3))) void*)l, 4, 0, 0);
}

#define BUF_BYTES 34816
#define OFS_B     16384
#define OFS_AS    32768
#define OFS_BS    33792

__global__ __launch_bounds__(512, 2) void gemm4_bias(
    const u8* __restrict__ A4, const u8* __restrict__ AS,
    const u8* __restrict__ B4, const u8* __restrict__ BS,
    const float* __restrict__ bias, float* __restrict__ C,
    int M, int N, int K)
{
    __shared__ __align__(16) u8 smem[3 * BUF_BYTES];   // 104448 B -> 1 block/CU

    const int tid  = threadIdx.x;
    const int wave = tid >> 6;
    const int lane = tid & 63;
    const int l31  = lane & 31;
    const int lhi  = lane >> 5;
    const int wm   = wave >> 2;   // 2 (M) x 4 (N) wave grid
    const int wn   = wave & 3;
    const int ntk  = K >> 7;
    const int NT   = ntk;

    // XCD-chunked + L2-grouped block ordering
    const int nbn = N >> 8;
    const int nbm = M >> 8;
    int bid = blockIdx.x;
    int bm, bn;
    if (((gridDim.x & 7) == 0) && ((nbm & 7) == 0)) {
        int bpc = nbm >> 3;                 // bm-panels per XCD chunk (pow2)
        int lb  = __builtin_ctz(bpc);
        int c   = bid & 7;
        int r   = bid >> 3;
        bm = c * bpc + (r & (bpc - 1));
        bn = r >> lb;
    } else {
        bn = bid % nbn;
        bm = bid / nbn;
    }

    v16f acc[4][2];
#pragma unroll
    for (int i = 0; i < 4; ++i)
#pragma unroll
        for (int j = 0; j < 2; ++j)
#pragma unroll
            for (int r = 0; r < 16; ++r) acc[i][j][r] = 0.f;

    // ---- staging constants
    const size_t aRow0 = (size_t)(2 * bm) * ntk;   // A tile-index base
    const size_t bRow0 = (size_t)(2 * bn) * ntk;
    const int isA = (wave < 4);
    const int w4  = wave & 3;
    const u8* scB = isA ? AS : BS;
    const size_t scT = (size_t)((isA ? 2 * bm : 2 * bn) + (w4 >> 1)) * ntk;
    const int scInner = (w4 & 1) * 256 + lane * 4;
    const int scDst   = (isA ? OFS_AS : OFS_BS) + w4 * 256;  // wave-uniform
    const int gOfs = wave * 1024 + lane * 16;  // per-lane global offset in 8KB round
    const int lOfs = wave * 1024;              // wave-uniform LDS offset

#define STG_A(bofs, kt, r)                                                    \
    gload16(A4 + ((aRow0 + (size_t)(r) * ntk + (kt)) << 13) + gOfs,           \
            smem + (bofs) + (r) * 8192 + lOfs)
#define STG_B(bofs, kt, r)                                                    \
    gload16(B4 + ((bRow0 + (size_t)(r) * ntk + (kt)) << 13) + gOfs,           \
            smem + (bofs) + OFS_B + (r) * 8192 + lOfs)
#define STG_S(bofs, kt)                                                       \
    gload4(scB + ((scT + (kt)) << 9) + scInner, smem + (bofs) + scDst)

#define RD_A(dst, mi, ks)                                                     \
    do {                                                                      \
        v4i t_ = *(const v4i*)(smem + cofs + wm * 8192                        \
                               + ((ks) * 2 + lhi) * 2048                      \
                               + ((mi) * 32 + l31) * 16);                     \
        dst = __builtin_shufflevector(t_, t_, 0, 1, 2, 3, -1, -1, -1, -1);    \
    } while (0)
#define RD_B(dst, ni, ks)                                                     \
    do {                                                                      \
        v4i t_ = *(const v4i*)(smem + cofs + OFS_B + (wn >> 1) * 8192         \
                               + ((ks) * 2 + lhi) * 2048                      \
                               + (((wn & 1) * 64 + (ni) * 32 + l31)) * 16);   \
        dst = __builtin_shufflevector(t_, t_, 0, 1, 2, 3, -1, -1, -1, -1);    \
    } while (0)

#define PH_SYNC()                                                             \
    do {                                                                      \
        __builtin_amdgcn_s_barrier();                                         \
        asm volatile("s_waitcnt lgkmcnt(0)" ::: "memory");                    \
        __builtin_amdgcn_sched_barrier(0);                                    \
        __builtin_amdgcn_s_setprio(1);                                        \
    } while (0)
#define PH_END()                                                              \
    do {                                                                      \
        __builtin_amdgcn_s_setprio(0);                                        \
        __builtin_amdgcn_s_barrier();                                         \
    } while (0)

#define MFMA4(aF0, aF1, miA, miB, ks)                                         \
    do {                                                                      \
        int sA0_ = (int)((saL[miA] >> ((ks) * 16)) & 0xffu);                  \
        int sA1_ = (int)((saL[miB] >> ((ks) * 16)) & 0xffu);                  \
        int sB0_ = (int)((sbL[0] >> ((ks) * 16)) & 0xffu);                    \
        int sB1_ = (int)((sbL[1] >> ((ks) * 16)) & 0xffu);                    \
        acc[miA][0] = __builtin_amdgcn_mfma_scale_f32_32x32x64_f8f6f4(        \
            aF0, bf0, acc[miA][0], 4, 4, 0, sA0_, 0, sB0_);                   \
        acc[miA][1] = __builtin_amdgcn_mfma_scale_f32_32x32x64_f8f6f4(        \
            aF0, bf1, acc[miA][1], 4, 4, 0, sA0_, 0, sB1_);                   \
        acc[miB][0] = __builtin_amdgcn_mfma_scale_f32_32x32x64_f8f6f4(        \
            aF1, bf0, acc[miB][0], 4, 4, 0, sA1_, 0, sB0_);                   \
        acc[miB][1] = __builtin_amdgcn_mfma_scale_f32_32x32x64_f8f6f4(        \
            aF1, bf1, acc[miB][1], 4, 4, 0, sA1_, 0, sB1_);                   \
    } while (0)

    // ---- prologue: stage tiles 0 and 1 (5 loads/wave each)
    STG_A(0, 0, 0); STG_A(0, 0, 1); STG_B(0, 0, 0); STG_B(0, 0, 1); STG_S(0, 0);
    STG_A(BUF_BYTES, 1, 0); STG_A(BUF_BYTES, 1, 1);
    STG_B(BUF_BYTES, 1, 0); STG_B(BUF_BYTES, 1, 1); STG_S(BUF_BYTES, 1);
    asm volatile("s_waitcnt vmcnt(5)" ::: "memory");   // tile 0 landed
    __builtin_amdgcn_s_barrier();

    int cofs = 0;
    int pofs = 2 * BUF_BYTES;
    for (int t = 0; t < NT; ++t) {
        const bool st = (t + 2 < NT);
        const int kt2 = t + 2;
        u32 saL[4], sbL[2];
        v8i af0, af1, bf0, bf1;

        // -- phase 0 (ks=0): scales + af01 + bf01 ; stage A r0,r1 of t+2
#pragma unroll
        for (int mi = 0; mi < 4; ++mi)
            saL[mi] = (*(const u32*)(smem + cofs + OFS_AS
                                     + (wm * 128 + mi * 32 + l31) * 4)) >> (lhi * 8);
#pragma unroll
        for (int ni = 0; ni < 2; ++ni)
            sbL[ni] = (*(const u32*)(smem + cofs + OFS_BS
                                     + (wn * 64 + ni * 32 + l31) * 4)) >> (lhi * 8);
        RD_A(af0, 0, 0); RD_A(af1, 1, 0); RD_B(bf0, 0, 0); RD_B(bf1, 1, 0);
        if (st) { STG_A(pofs, kt2, 0); STG_A(pofs, kt2, 1); }
        PH_SYNC();
        MFMA4(af0, af1, 0, 1, 0);
        PH_END();

        // -- phase 1 (ks=0): af23 ; stage B r0
        RD_A(af0, 2, 0); RD_A(af1, 3, 0);
        if (st) STG_B(pofs, kt2, 0);
        PH_SYNC();
        MFMA4(af0, af1, 2, 3, 0);
        PH_END();

        // -- phase 2 (ks=1): af01 + bf01 ; stage B r1
        RD_A(af0, 0, 1); RD_A(af1, 1, 1); RD_B(bf0, 0, 1); RD_B(bf1, 1, 1);
        if (st) STG_B(pofs, kt2, 1);
        PH_SYNC();
        MFMA4(af0, af1, 0, 1, 1);
        PH_END();

        // -- phase 3 (ks=1): af23 ; stage scales
        RD_A(af0, 2, 1); RD_A(af1, 3, 1);
        if (st) STG_S(pofs, kt2);
        PH_SYNC();
        MFMA4(af0, af1, 2, 3, 1);
        __builtin_amdgcn_s_setprio(0);
        // K-tile boundary: buf[(t+1)%3]'s 5 loads (issued a full tile ago)
        // must land; t+2's 5 stay in flight. Counted, never 0 mid-loop.
        if (st) asm volatile("s_waitcnt vmcnt(5)" ::: "memory");
        else    asm volatile("s_waitcnt vmcnt(0)" ::: "memory");
        __builtin_amdgcn_s_barrier();

        cofs += BUF_BYTES; if (cofs == 3 * BUF_BYTES) cofs = 0;
        pofs += BUF_BYTES; if (pofs == 3 * BUF_BYTES) pofs = 0;
    }

    // Epilogue: 32x32 C/D: col = lane&31, row = (reg&3)+8*(reg>>2)+4*(lane>>5)
    const int cb = bn * 256 + wn * 64;
    const int rb = bm * 256 + wm * 128;
#pragma unroll
    for (int ni = 0; ni < 2; ++ni) {
        float bb = bias[cb + ni * 32 + l31];
#pragma unroll
        for (int mi = 0; mi < 4; ++mi) {
#pragma unroll
            for (int reg = 0; reg < 16; ++reg) {
                int row = (reg & 3) + 8 * (reg >> 2) + 4 * lhi;
                C[(size_t)(rb + mi * 32 + row) * N + cb + ni * 32 + l31]
                    = acc[mi][ni][reg] + bb;
            }
        }
    }
#undef STG_A
#undef STG_B
#undef STG_S
#undef RD_A
#undef RD_B
#undef PH_SYNC
#undef PH_END
#undef MFMA4
}

// ---------------------------------------------------------------------------
extern "C" void kernel_launch(void* const* d_in, const int* in_sizes, int n_in,
                              void* d_out, int out_size, void* d_ws, size_t ws_size,
                              hipStream_t stream)
{
    const float* x    = (const float*)d_in[0];   // [M, K] = [8192, 4096]
    const float* w    = (const float*)d_in[1];   // [O, K] = [16384, 4096]
    const float* bias = (const float*)d_in[2];   // [O]

    const int O = in_sizes[2];            // 16384
    const int K = in_sizes[1] / O;        // 4096
    const int M = in_sizes[0] / K;        // 8192

    u8* x4 = (u8*)d_ws;                           // [M, K/2]  tiled
    u8* w4 = x4 + (size_t)M * (K / 2);            // [O, K/2]  tiled
    u8* xs = w4 + (size_t)O * (K / 2);            // [M, K/32] tiled
    u8* ws = xs + (size_t)M * (K / 32);           // [O, K/32] tiled

    const int gpr = K / 32;
    const int ntk = K / 128;
    const int gx = M * gpr;
    const int gw = O * gpr;
    rotquant4_kernel<<<(gx + 255) / 256, 256, 0, stream>>>(x, x4, xs, gx, gpr, ntk);
    rotquant4_kernel<<<(gw + 255) / 256, 256, 0, stream>>>(w, w4, ws, gw, gpr, ntk);

    dim3 grid((M / 256) * (O / 256));     // 2048 blocks
    gemm4_bias<<<grid, 512, 0, stream>>>(x4, xs, w4, ws, bias, (float*)d_out,
                                         M, O, K);
}

// Round 7
// 490.874 us; speedup vs baseline: 1.0363x; 1.0363x over previous
//
#include <hip/hip_runtime.h>

typedef unsigned short u16;
typedef unsigned int u32;
typedef unsigned char u8;
typedef int v8i __attribute__((ext_vector_type(8)));
typedef int v4i __attribute__((ext_vector_type(4)));
typedef float v16f __attribute__((ext_vector_type(16)));

#define INV_SQRT32 0.17677669529663688f

// ---------------------------------------------------------------------------
// Stage 1: per-32-group FWHT + MXFP4 quantize, memory-pattern optimized.
// Block = 256 threads covering 8 rows x 1024 K-elements (32 groups x 32 elems
// per row-slice). Coalesced float4 loads -> swizzled LDS -> per-thread FWHT
// (identical math to rounds 1-6) -> LDS repack -> coalesced tiled stores.
// Output layout UNCHANGED (tile = 128 rows x 128 k):
//   data chunk16 (row, kb): (tile)*8192 + (kb&3)*2048 + (row&127)*16
//   scale byte  (row, kb): tile*512 + (row&127)*4 + (kb&3)
// ---------------------------------------------------------------------------
#define QOFS_OUT 32768
#define QOFS_SC  36864

__global__ __launch_bounds__(256) void rotquant4_kernel(
    const float* __restrict__ T, u8* __restrict__ Q4, u8* __restrict__ S,
    int K, int ntk, int nkb /* K/1024 */)
{
    __shared__ __align__(16) u8 smem[37120];

    const int tid  = threadIdx.x;
    const int bid  = blockIdx.x;
    const int rblk = bid / nkb;
    const int kblk = bid - rblk * nkb;
    const int row0 = rblk * 8;
    const int kb0  = kblk * 32;
    const int t0g  = (row0 >> 7) * ntk + (kb0 >> 2);   // first tile index
    const int rl   = row0 & 127;                        // row0 within panel

    // ---- load 8 rows x 1024 floats, coalesced; swizzled LDS layout:
    // byte = r*4096 + kb*128 + ((i ^ (kb&7))<<4)   (kb,i local: kb=ci>>3,i=ci&7)
    {
        const float4* src = (const float4*)T;
#pragma unroll
        for (int j = 0; j < 8; ++j) {
            float4 t = src[(size_t)(row0 + j) * (K >> 2) + (kblk << 8) + tid];
            int kb = tid >> 3, i = tid & 7;
            *(float4*)(smem + j * 4096 + kb * 128 + ((i ^ (kb & 7)) << 4)) = t;
        }
    }
    __syncthreads();

    // ---- per-thread group compute (math identical to proven rounds 1-6)
    {
        const int rr = tid >> 5;     // local row 0..7
        const int kb = tid & 31;     // local group 0..31

        float v[32];
#pragma unroll
        for (int i = 0; i < 8; ++i) {
            float4 t = *(const float4*)(smem + rr * 4096 + kb * 128
                                        + ((i ^ (kb & 7)) << 4));
            v[i*4+0] = t.x; v[i*4+1] = t.y; v[i*4+2] = t.z; v[i*4+3] = t.w;
        }

#pragma unroll
        for (int s = 1; s < 32; s <<= 1) {
#pragma unroll
            for (int i = 0; i < 32; ++i) {
                if (!(i & s)) {
                    float a = v[i], b = v[i | s];
                    v[i] = a + b;
                    v[i | s] = a - b;
                }
            }
        }

        float amax = 0.f;
#pragma unroll
        for (int i = 0; i < 32; ++i) {
            v[i] *= INV_SQRT32;
            amax = fmaxf(amax, fabsf(v[i]));
        }

        u32 ab = __float_as_uint(amax);
        int be = (int)(ab >> 23);
        u32 w[4] = {0u, 0u, 0u, 0u};
        u8 sbyte = 0;
        if (be >= 3) {
            sbyte = (u8)(be - 2);               // E8M0 of 2^(be-129)
            float iscale = __uint_as_float((u32)(256 - be) << 23);
#pragma unroll
            for (int i = 0; i < 32; ++i) {
                float a = v[i] * iscale;        // exact
                float m = fminf(fabsf(a), 6.0f);
                int c = (m < 0.25f) ? 0 :
                        (m < 0.75f) ? 1 :
                        (m < 1.25f) ? 2 :
                        (m < 1.75f) ? 3 :
                        (m < 2.5f)  ? 4 :
                        (m < 3.5f)  ? 5 :
                        (m < 5.0f)  ? 6 : 7;
                c |= (int)((__float_as_uint(a) >> 28) & 8u);
                w[i >> 3] |= (u32)c << (4 * (i & 7));
            }
        }

        // stage to LDS: data [row8][tile8][slot4][16B], scales [row8][tile8][slot4]
        uint4 p; p.x = w[0]; p.y = w[1]; p.z = w[2]; p.w = w[3];
        *(uint4*)(smem + QOFS_OUT + rr * 512 + (kb >> 2) * 64 + (kb & 3) * 16) = p;
        smem[QOFS_SC + rr * 32 + (kb >> 2) * 4 + (kb & 3)] = sbyte;
    }
    __syncthreads();

    // ---- coalesced output copy: data (4KB) + scales (256B)
    {
        int tileL = tid >> 5, slot = (tid >> 3) & 3, rr = tid & 7;
        uint4 p = *(const uint4*)(smem + QOFS_OUT + rr * 512 + tileL * 64
                                  + slot * 16);
        ((uint4*)Q4)[(size_t)(t0g + tileL) * 512 + slot * 128 + rl + rr] = p;
    }
    if (tid < 64) {
        int tileL = tid >> 3, rr = tid & 7;
        u32 sc = *(const u32*)(smem + QOFS_SC + rr * 32 + tileL * 4);
        ((u32*)S)[(size_t)(t0g + tileL) * 128 + rl + rr] = sc;
    }
}

// ---------------------------------------------------------------------------
// Stage 2: C = deq(A) * deq(B)^T + bias via MX-scaled FP4 MFMA.
// BM=256, BN=256, BK=128, 8 waves (2Mx4N), per-wave 128x64 (4x2 reg-block).
// Rolling register pipeline: per K-tile {STAGE t+2 || read ks1 || MFMA8(ks0)}
// -> vmcnt(5) -> barrier -> {read t+1 ks0 + scales || MFMA8(ks1)}.
// Triple-buffered LDS, ONE barrier + ONE counted waitcnt per K-tile.
// ---------------------------------------------------------------------------
__device__ __forceinline__ void gload16(const void* g, void* l)
{
    __builtin_amdgcn_global_load_lds(
        (__attribute__((address_space(1))) void*)g,
        (__attribute__((address_space(3))) void*)l, 16, 0, 0);
}
__device__ __forceinline__ void gload4(const void* g, void* l)
{
    __builtin_amdgcn_global_load_lds(
        (__attribute__((address_space(1))) void*)g,
        (__attribute__((address_space(3))) void*)l, 4, 0, 0);
}

#define BUF_BYTES 34816
#define OFS_B     16384
#define OFS_AS    32768
#define OFS_BS    33792

__global__ __launch_bounds__(512, 2) void gemm4_bias(
    const u8* __restrict__ A4, const u8* __restrict__ AS,
    const u8* __restrict__ B4, const u8* __restrict__ BS,
    const float* __restrict__ bias, float* __restrict__ C,
    int M, int N, int K)
{
    __shared__ __align__(16) u8 smem[3 * BUF_BYTES];   // 104448 B

    const int tid  = threadIdx.x;
    const int wave = tid >> 6;
    const int lane = tid & 63;
    const int l31  = lane & 31;
    const int lhi  = lane >> 5;
    const int wm   = wave >> 2;   // 2 (M) x 4 (N) wave grid
    const int wn   = wave & 3;
    const int ntk  = K >> 7;
    const int NT   = ntk;

    // XCD-chunked + L2-grouped block ordering
    const int nbn = N >> 8;
    const int nbm = M >> 8;
    int bid = blockIdx.x;
    int bm, bn;
    if (((gridDim.x & 7) == 0) && ((nbm & 7) == 0)) {
        int bpc = nbm >> 3;
        int lb  = __builtin_ctz(bpc);
        int c   = bid & 7;
        int r   = bid >> 3;
        bm = c * bpc + (r & (bpc - 1));
        bn = r >> lb;
    } else {
        bn = bid % nbn;
        bm = bid / nbn;
    }

    v16f acc[4][2];
#pragma unroll
    for (int i = 0; i < 4; ++i)
#pragma unroll
        for (int j = 0; j < 2; ++j)
#pragma unroll
            for (int r = 0; r < 16; ++r) acc[i][j][r] = 0.f;

    // ---- staging constants
    const size_t aRow0 = (size_t)(2 * bm) * ntk;
    const size_t bRow0 = (size_t)(2 * bn) * ntk;
    const int isA = (wave < 4);
    const int w4  = wave & 3;
    const u8* scB = isA ? AS : BS;
    const size_t scT = (size_t)((isA ? 2 * bm : 2 * bn) + (w4 >> 1)) * ntk;
    const int scInner = (w4 & 1) * 256 + lane * 4;
    const int scDst   = (isA ? OFS_AS : OFS_BS) + w4 * 256;
    const int gOfs = wave * 1024 + lane * 16;
    const int lOfs = wave * 1024;

#define STG_A(bofs, kt, r)                                                    \
    gload16(A4 + ((aRow0 + (size_t)(r) * ntk + (kt)) << 13) + gOfs,           \
            smem + (bofs) + (r) * 8192 + lOfs)
#define STG_B(bofs, kt, r)                                                    \
    gload16(B4 + ((bRow0 + (size_t)(r) * ntk + (kt)) << 13) + gOfs,           \
            smem + (bofs) + OFS_B + (r) * 8192 + lOfs)
#define STG_S(bofs, kt)                                                       \
    gload4(scB + ((scT + (kt)) << 9) + scInner, smem + (bofs) + scDst)
#define STAGE(bofs, kt)                                                       \
    do { STG_A(bofs, kt, 0); STG_A(bofs, kt, 1);                              \
         STG_B(bofs, kt, 0); STG_B(bofs, kt, 1); STG_S(bofs, kt); } while (0)

#define LDSC(dsa, dsb, ofs)                                                   \
    do {                                                                      \
        _Pragma("unroll")                                                     \
        for (int mi = 0; mi < 4; ++mi)                                        \
            dsa[mi] = (*(const u32*)(smem + (ofs) + OFS_AS                    \
                          + (wm * 128 + mi * 32 + l31) * 4)) >> (lhi * 8);    \
        _Pragma("unroll")                                                     \
        for (int ni = 0; ni < 2; ++ni)                                        \
            dsb[ni] = (*(const u32*)(smem + (ofs) + OFS_BS                    \
                          + (wn * 64 + ni * 32 + l31) * 4)) >> (lhi * 8);     \
    } while (0)

#define RD_SET(AF, BF, ks, ofs)                                               \
    do {                                                                      \
        _Pragma("unroll")                                                     \
        for (int mi = 0; mi < 4; ++mi) {                                      \
            v4i t_ = *(const v4i*)(smem + (ofs) + wm * 8192                   \
                                   + ((ks) * 2 + lhi) * 2048                  \
                                   + ((mi) * 32 + l31) * 16);                 \
            AF[mi] = __builtin_shufflevector(t_, t_, 0,1,2,3,-1,-1,-1,-1);    \
        }                                                                     \
        _Pragma("unroll")                                                     \
        for (int ni = 0; ni < 2; ++ni) {                                      \
            v4i t_ = *(const v4i*)(smem + (ofs) + OFS_B + (wn >> 1) * 8192    \
                                   + ((ks) * 2 + lhi) * 2048                  \
                                   + ((wn & 1) * 64 + (ni) * 32 + l31) * 16); \
            BF[ni] = __builtin_shufflevector(t_, t_, 0,1,2,3,-1,-1,-1,-1);    \
        }                                                                     \
    } while (0)

#define MFMA_PH(AF, BF, ks)                                                   \
    do {                                                                      \
        _Pragma("unroll")                                                     \
        for (int mi = 0; mi < 4; ++mi) {                                      \
            int sA_ = (int)((sa[mi] >> ((ks) * 16)) & 0xffu);                 \
            _Pragma("unroll")                                                 \
            for (int ni = 0; ni < 2; ++ni) {                                  \
                int sB_ = (int)((sb[ni] >> ((ks) * 16)) & 0xffu);             \
                acc[mi][ni] = __builtin_amdgcn_mfma_scale_f32_32x32x64_f8f6f4(\
                    AF[mi], BF[ni], acc[mi][ni], 4, 4, 0, sA_, 0, sB_);       \
            }                                                                 \
        }                                                                     \
    } while (0)

    // ---- prologue: stage tiles 0,1; land tile 0; preload its ks0 operands
    STAGE(0, 0);
    STAGE(BUF_BYTES, 1);
    asm volatile("s_waitcnt vmcnt(5)" ::: "memory");
    __builtin_amdgcn_s_barrier();

    u32 sa[4], sb[2];
    v8i Af[4], Bf[2], Cf[4], Df[2];
    LDSC(sa, sb, 0);
    RD_SET(Af, Bf, 0, 0);

    int cofs = 0, nofs = BUF_BYTES, pofs = 2 * BUF_BYTES;
    for (int t = 0; t < NT; ++t) {
        const bool st = (t + 2 < NT);
        if (st) STAGE(pofs, t + 2);
        RD_SET(Cf, Df, 1, cofs);
        __builtin_amdgcn_s_setprio(1);
        MFMA_PH(Af, Bf, 0);
        __builtin_amdgcn_s_setprio(0);
        if (st) asm volatile("s_waitcnt vmcnt(5)" ::: "memory");
        else    asm volatile("s_waitcnt vmcnt(0)" ::: "memory");
        __builtin_amdgcn_s_barrier();
        u32 tsa[4] = {0,0,0,0}, tsb[2] = {0,0};
        if (t + 1 < NT) {
            LDSC(tsa, tsb, nofs);
            RD_SET(Af, Bf, 0, nofs);
        }
        __builtin_amdgcn_s_setprio(1);
        MFMA_PH(Cf, Df, 1);
        __builtin_amdgcn_s_setprio(0);
#pragma unroll
        for (int i = 0; i < 4; ++i) sa[i] = tsa[i];
#pragma unroll
        for (int i = 0; i < 2; ++i) sb[i] = tsb[i];
        int old = cofs;
        cofs = nofs; nofs = pofs; pofs = old;
    }

    // Epilogue: 32x32 C/D: col = lane&31, row = (reg&3)+8*(reg>>2)+4*(lane>>5)
    const int cb = bn * 256 + wn * 64;
    const int rb = bm * 256 + wm * 128;
#pragma unroll
    for (int ni = 0; ni < 2; ++ni) {
        float bb = bias[cb + ni * 32 + l31];
#pragma unroll
        for (int mi = 0; mi < 4; ++mi) {
#pragma unroll
            for (int reg = 0; reg < 16; ++reg) {
                int row = (reg & 3) + 8 * (reg >> 2) + 4 * lhi;
                C[(size_t)(rb + mi * 32 + row) * N + cb + ni * 32 + l31]
                    = acc[mi][ni][reg] + bb;
            }
        }
    }
#undef STG_A
#undef STG_B
#undef STG_S
#undef STAGE
#undef LDSC
#undef RD_SET
#undef MFMA_PH
}

// ---------------------------------------------------------------------------
extern "C" void kernel_launch(void* const* d_in, const int* in_sizes, int n_in,
                              void* d_out, int out_size, void* d_ws, size_t ws_size,
                              hipStream_t stream)
{
    const float* x    = (const float*)d_in[0];   // [M, K] = [8192, 4096]
    const float* w    = (const float*)d_in[1];   // [O, K] = [16384, 4096]
    const float* bias = (const float*)d_in[2];   // [O]

    const int O = in_sizes[2];            // 16384
    const int K = in_sizes[1] / O;        // 4096
    const int M = in_sizes[0] / K;        // 8192

    u8* x4 = (u8*)d_ws;                           // [M, K/2]  tiled
    u8* w4 = x4 + (size_t)M * (K / 2);            // [O, K/2]  tiled
    u8* xs = w4 + (size_t)O * (K / 2);            // [M, K/32] tiled
    u8* ws = xs + (size_t)M * (K / 32);           // [O, K/32] tiled

    const int ntk = K / 128;
    const int nkb = K / 1024;
    rotquant4_kernel<<<(M / 8) * nkb, 256, 0, stream>>>(x, x4, xs, K, ntk, nkb);
    rotquant4_kernel<<<(O / 8) * nkb, 256, 0, stream>>>(w, w4, ws, K, ntk, nkb);

    dim3 grid((M / 256) * (O / 256));     // 2048 blocks
    gemm4_bias<<<grid, 512, 0, stream>>>(x4, xs, w4, ws, bias, (float*)d_out,
                                         M, O, K);
}

// Round 8
// 454.731 us; speedup vs baseline: 1.1186x; 1.0795x over previous
//
#include <hip/hip_runtime.h>

typedef unsigned short u16;
typedef unsigned int u32;
typedef unsigned char u8;
typedef int v8i __attribute__((ext_vector_type(8)));
typedef int v4i __attribute__((ext_vector_type(4)));
typedef float v16f __attribute__((ext_vector_type(16)));

#define INV_SQRT32 0.17677669529663688f

// ---------------------------------------------------------------------------
// Stage 1: per-32-group FWHT + MXFP4 quantize (UNCHANGED from round 7).
// Block = 8 rows x 1024 K. Coalesced float4 loads -> swizzled LDS ->
// per-thread FWHT/quant (proven math) -> LDS repack -> coalesced tiled store.
// Output layout (tile = 128 rows x 128 k):
//   data chunk16 (row, kb): tile*8192 + (kb&3)*2048 + (row&127)*16
//   scale byte  (row, kb): tile*512 + (row&127)*4 + (kb&3)
// ---------------------------------------------------------------------------
#define QOFS_OUT 32768
#define QOFS_SC  36864

__global__ __launch_bounds__(256) void rotquant4_kernel(
    const float* __restrict__ T, u8* __restrict__ Q4, u8* __restrict__ S,
    int K, int ntk, int nkb /* K/1024 */)
{
    __shared__ __align__(16) u8 smem[37120];

    const int tid  = threadIdx.x;
    const int bid  = blockIdx.x;
    const int rblk = bid / nkb;
    const int kblk = bid - rblk * nkb;
    const int row0 = rblk * 8;
    const int kb0  = kblk * 32;
    const int t0g  = (row0 >> 7) * ntk + (kb0 >> 2);
    const int rl   = row0 & 127;

    {
        const float4* src = (const float4*)T;
#pragma unroll
        for (int j = 0; j < 8; ++j) {
            float4 t = src[(size_t)(row0 + j) * (K >> 2) + (kblk << 8) + tid];
            int kb = tid >> 3, i = tid & 7;
            *(float4*)(smem + j * 4096 + kb * 128 + ((i ^ (kb & 7)) << 4)) = t;
        }
    }
    __syncthreads();

    {
        const int rr = tid >> 5;
        const int kb = tid & 31;

        float v[32];
#pragma unroll
        for (int i = 0; i < 8; ++i) {
            float4 t = *(const float4*)(smem + rr * 4096 + kb * 128
                                        + ((i ^ (kb & 7)) << 4));
            v[i*4+0] = t.x; v[i*4+1] = t.y; v[i*4+2] = t.z; v[i*4+3] = t.w;
        }

#pragma unroll
        for (int s = 1; s < 32; s <<= 1) {
#pragma unroll
            for (int i = 0; i < 32; ++i) {
                if (!(i & s)) {
                    float a = v[i], b = v[i | s];
                    v[i] = a + b;
                    v[i | s] = a - b;
                }
            }
        }

        float amax = 0.f;
#pragma unroll
        for (int i = 0; i < 32; ++i) {
            v[i] *= INV_SQRT32;
            amax = fmaxf(amax, fabsf(v[i]));
        }

        u32 ab = __float_as_uint(amax);
        int be = (int)(ab >> 23);
        u32 w[4] = {0u, 0u, 0u, 0u};
        u8 sbyte = 0;
        if (be >= 3) {
            sbyte = (u8)(be - 2);               // E8M0 of 2^(be-129)
            float iscale = __uint_as_float((u32)(256 - be) << 23);
#pragma unroll
            for (int i = 0; i < 32; ++i) {
                float a = v[i] * iscale;        // exact
                float m = fminf(fabsf(a), 6.0f);
                int c = (m < 0.25f) ? 0 :
                        (m < 0.75f) ? 1 :
                        (m < 1.25f) ? 2 :
                        (m < 1.75f) ? 3 :
                        (m < 2.5f)  ? 4 :
                        (m < 3.5f)  ? 5 :
                        (m < 5.0f)  ? 6 : 7;
                c |= (int)((__float_as_uint(a) >> 28) & 8u);
                w[i >> 3] |= (u32)c << (4 * (i & 7));
            }
        }

        uint4 p; p.x = w[0]; p.y = w[1]; p.z = w[2]; p.w = w[3];
        *(uint4*)(smem + QOFS_OUT + rr * 512 + (kb >> 2) * 64 + (kb & 3) * 16) = p;
        smem[QOFS_SC + rr * 32 + (kb >> 2) * 4 + (kb & 3)] = sbyte;
    }
    __syncthreads();

    {
        int tileL = tid >> 5, slot = (tid >> 3) & 3, rr = tid & 7;
        uint4 p = *(const uint4*)(smem + QOFS_OUT + rr * 512 + tileL * 64
                                  + slot * 16);
        ((uint4*)Q4)[(size_t)(t0g + tileL) * 512 + slot * 128 + rl + rr] = p;
    }
    if (tid < 64) {
        int tileL = tid >> 3, rr = tid & 7;
        u32 sc = *(const u32*)(smem + QOFS_SC + rr * 32 + tileL * 4);
        ((u32*)S)[(size_t)(t0g + tileL) * 128 + rl + rr] = sc;
    }
}

// ---------------------------------------------------------------------------
// Stage 2: C = deq(A) * deq(B)^T + bias via MX-scaled FP4 MFMA.
// BM=256, BN=256, BK=128, 8 waves (2Mx4N), per-wave 128x64 (4x2 reg-block).
// Triple-buffered LDS, K-loop UNROLLED BY 3 so all LDS offsets are
// compile-time constants. Per tile: STAGE t+2 -> 12 ds_read_b128 + 6 scale
// reads -> setprio(1) + 16 MFMA + setprio(0) -> s_waitcnt vmcnt(5) (counted;
// drain-0 only in 2-tile epilogue) -> one s_barrier.
// Requires (NT-2) % 3 == 0 (K=4096 -> NT=32 -> 30 ok).
// ---------------------------------------------------------------------------
__device__ __forceinline__ void gload16(const void* g, void* l)
{
    __builtin_amdgcn_global_load_lds(
        (__attribute__((address_space(1))) void*)g,
        (__attribute__((address_space(3))) void*)l, 16, 0, 0);
}
__device__ __forceinline__ void gload4(const void* g, void* l)
{
    __builtin_amdgcn_global_load_lds(
        (__attribute__((address_space(1))) void*)g,
        (__attribute__((address_space(3))) void*)l, 4, 0, 0);
}

#define BUF_BYTES 34816
#define OFS_B     16384
#define OFS_AS    32768
#define OFS_BS    33792
#define BB0 0
#define BB1 BUF_BYTES
#define BB2 (2 * BUF_BYTES)

__global__ __launch_bounds__(512, 2) void gemm4_bias(
    const u8* __restrict__ A4, const u8* __restrict__ AS,
    const u8* __restrict__ B4, const u8* __restrict__ BS,
    const float* __restrict__ bias, float* __restrict__ C,
    int M, int N, int K)
{
    __shared__ __align__(16) u8 smem[3 * BUF_BYTES];   // 104448 B

    const int tid  = threadIdx.x;
    const int wave = tid >> 6;
    const int lane = tid & 63;
    const int l31  = lane & 31;
    const int lhi  = lane >> 5;
    const int wm   = wave >> 2;   // 2 (M) x 4 (N) wave grid
    const int wn   = wave & 3;
    const int ntk  = K >> 7;
    const int NT   = ntk;

    // XCD-chunked + L2-grouped block ordering
    const int nbn = N >> 8;
    const int nbm = M >> 8;
    int bid = blockIdx.x;
    int bm, bn;
    if (((gridDim.x & 7) == 0) && ((nbm & 7) == 0)) {
        int bpc = nbm >> 3;
        int lb  = __builtin_ctz(bpc);
        int c   = bid & 7;
        int r   = bid >> 3;
        bm = c * bpc + (r & (bpc - 1));
        bn = r >> lb;
    } else {
        bn = bid % nbn;
        bm = bid / nbn;
    }

    v16f acc[4][2];
#pragma unroll
    for (int i = 0; i < 4; ++i)
#pragma unroll
        for (int j = 0; j < 2; ++j)
#pragma unroll
            for (int r = 0; r < 16; ++r) acc[i][j][r] = 0.f;

    // ---- staging constants
    const size_t aRow0 = (size_t)(2 * bm) * ntk;
    const size_t bRow0 = (size_t)(2 * bn) * ntk;
    const int isA = (wave < 4);
    const int w4  = wave & 3;
    const u8* scB = isA ? AS : BS;
    const size_t scT = (size_t)((isA ? 2 * bm : 2 * bn) + (w4 >> 1)) * ntk;
    const int scInner = (w4 & 1) * 256 + lane * 4;
    const int scDst   = (isA ? OFS_AS : OFS_BS) + w4 * 256;
    const int gOfs = wave * 1024 + lane * 16;
    const int lOfs = wave * 1024;

    // ---- per-lane LDS read bases (byte offsets within ONE buffer)
    const int aRB   = wm * 8192 + lhi * 2048 + l31 * 16;          // +mi*512 +ks*4096
    const int bRB   = OFS_B + (wn >> 1) * 8192 + lhi * 2048
                      + (wn & 1) * 1024 + l31 * 16;               // +ni*512 +ks*4096
    const int asB   = OFS_AS + wm * 512 + l31 * 4;                // +mi*128
    const int bsB   = OFS_BS + wn * 256 + l31 * 4;                // +ni*128
    const int shamt = lhi * 8;

#define STG_A(bofs, kt, r)                                                    \
    gload16(A4 + ((aRow0 + (size_t)(r) * ntk + (kt)) << 13) + gOfs,           \
            smem + (bofs) + (r) * 8192 + lOfs)
#define STG_B(bofs, kt, r)                                                    \
    gload16(B4 + ((bRow0 + (size_t)(r) * ntk + (kt)) << 13) + gOfs,           \
            smem + (bofs) + OFS_B + (r) * 8192 + lOfs)
#define STG_S(bofs, kt)                                                       \
    gload4(scB + ((scT + (kt)) << 9) + scInner, smem + (bofs) + scDst)
#define STAGE(bofs, kt)                                                       \
    do { STG_A(bofs, kt, 0); STG_A(bofs, kt, 1);                              \
         STG_B(bofs, kt, 0); STG_B(bofs, kt, 1); STG_S(bofs, kt); } while (0)

#define MK8(x) __builtin_shufflevector(x, x, 0, 1, 2, 3, -1, -1, -1, -1)
#define MFMA1(mi, ni, AF, BF, SA, SB)                                         \
    acc[mi][ni] = __builtin_amdgcn_mfma_scale_f32_32x32x64_f8f6f4(            \
        MK8(AF), MK8(BF), acc[mi][ni], 4, 4, 0, (int)(SA), 0, (int)(SB))
#define CL8(A0, A1, A2, A3, Bx0, Bx1, S0, S1, S2, S3, T0, T1)                 \
    do {                                                                      \
        MFMA1(0, 0, A0, Bx0, S0, T0); MFMA1(0, 1, A0, Bx1, S0, T1);           \
        MFMA1(1, 0, A1, Bx0, S1, T0); MFMA1(1, 1, A1, Bx1, S1, T1);           \
        MFMA1(2, 0, A2, Bx0, S2, T0); MFMA1(2, 1, A2, Bx1, S2, T1);           \
        MFMA1(3, 0, A3, Bx0, S3, T0); MFMA1(3, 1, A3, Bx1, S3, T1);           \
    } while (0)

#define TILE(CO, PO, kt, ST, FINAL)                                           \
    do {                                                                      \
        if (ST) STAGE(PO, (kt) + 2);                                          \
        u32 sa0 = (*(const u32*)(smem + (CO) + asB      )) >> shamt;          \
        u32 sa1 = (*(const u32*)(smem + (CO) + asB + 128)) >> shamt;          \
        u32 sa2 = (*(const u32*)(smem + (CO) + asB + 256)) >> shamt;          \
        u32 sa3 = (*(const u32*)(smem + (CO) + asB + 384)) >> shamt;          \
        u32 sb0 = (*(const u32*)(smem + (CO) + bsB      )) >> shamt;          \
        u32 sb1 = (*(const u32*)(smem + (CO) + bsB + 128)) >> shamt;          \
        v4i a00 = *(const v4i*)(smem + (CO) + aRB       );                    \
        v4i a01 = *(const v4i*)(smem + (CO) + aRB +  512);                    \
        v4i a02 = *(const v4i*)(smem + (CO) + aRB + 1024);                    \
        v4i a03 = *(const v4i*)(smem + (CO) + aRB + 1536);                    \
        v4i b00 = *(const v4i*)(smem + (CO) + bRB       );                    \
        v4i b01 = *(const v4i*)(smem + (CO) + bRB +  512);                    \
        v4i a10 = *(const v4i*)(smem + (CO) + aRB + 4096);                    \
        v4i a11 = *(const v4i*)(smem + (CO) + aRB + 4608);                    \
        v4i a12 = *(const v4i*)(smem + (CO) + aRB + 5120);                    \
        v4i a13 = *(const v4i*)(smem + (CO) + aRB + 5632);                    \
        v4i b10 = *(const v4i*)(smem + (CO) + bRB + 4096);                    \
        v4i b11 = *(const v4i*)(smem + (CO) + bRB + 4608);                    \
        __builtin_amdgcn_s_setprio(1);                                        \
        CL8(a00, a01, a02, a03, b00, b01,                                     \
            sa0 & 0xffu, sa1 & 0xffu, sa2 & 0xffu, sa3 & 0xffu,               \
            sb0 & 0xffu, sb1 & 0xffu);                                        \
        CL8(a10, a11, a12, a13, b10, b11,                                     \
            (sa0 >> 16) & 0xffu, (sa1 >> 16) & 0xffu,                         \
            (sa2 >> 16) & 0xffu, (sa3 >> 16) & 0xffu,                         \
            (sb0 >> 16) & 0xffu, (sb1 >> 16) & 0xffu);                        \
        __builtin_amdgcn_s_setprio(0);                                        \
        if (!(FINAL)) {                                                       \
            if (ST) { asm volatile("s_waitcnt vmcnt(5)" ::: "memory"); }      \
            else    { asm volatile("s_waitcnt vmcnt(0)" ::: "memory"); }      \
            __builtin_amdgcn_s_barrier();                                     \
        }                                                                     \
    } while (0)

    // ---- prologue: stage tiles 0,1; wait tile 0 (tile 1's 5 stay in flight)
    STAGE(BB0, 0);
    STAGE(BB1, 1);
    asm volatile("s_waitcnt vmcnt(5)" ::: "memory");
    __builtin_amdgcn_s_barrier();

    // main: tiles 0..NT-3 in rounds of 3 (all buffer offsets compile-time)
#pragma unroll 1
    for (int t = 0; t + 2 < NT; t += 3) {
        TILE(BB0, BB2, t + 0, true, false);
        TILE(BB1, BB0, t + 1, true, false);
        TILE(BB2, BB1, t + 2, true, false);
    }
    // epilogue: tiles NT-2 (buf0), NT-1 (buf1); (NT-2)%3==0 guarantees this
    TILE(BB0, BB2, NT - 2, false, false);   // vmcnt(0): last tile lands here
    TILE(BB1, BB2, NT - 1, false, true);

    // Epilogue: 32x32 C/D: col = lane&31, row = (reg&3)+8*(reg>>2)+4*(lane>>5)
    const int cb = bn * 256 + wn * 64;
    const int rb = bm * 256 + wm * 128;
#pragma unroll
    for (int ni = 0; ni < 2; ++ni) {
        float bb = bias[cb + ni * 32 + l31];
#pragma unroll
        for (int mi = 0; mi < 4; ++mi) {
#pragma unroll
            for (int reg = 0; reg < 16; ++reg) {
                int row = (reg & 3) + 8 * (reg >> 2) + 4 * lhi;
                C[(size_t)(rb + mi * 32 + row) * N + cb + ni * 32 + l31]
                    = acc[mi][ni][reg] + bb;
            }
        }
    }
#undef STG_A
#undef STG_B
#undef STG_S
#undef STAGE
#undef MK8
#undef MFMA1
#undef CL8
#undef TILE
}

// ---------------------------------------------------------------------------
extern "C" void kernel_launch(void* const* d_in, const int* in_sizes, int n_in,
                              void* d_out, int out_size, void* d_ws, size_t ws_size,
                              hipStream_t stream)
{
    const float* x    = (const float*)d_in[0];   // [M, K] = [8192, 4096]
    const float* w    = (const float*)d_in[1];   // [O, K] = [16384, 4096]
    const float* bias = (const float*)d_in[2];   // [O]

    const int O = in_sizes[2];            // 16384
    const int K = in_sizes[1] / O;        // 4096
    const int M = in_sizes[0] / K;        // 8192

    u8* x4 = (u8*)d_ws;                           // [M, K/2]  tiled
    u8* w4 = x4 + (size_t)M * (K / 2);            // [O, K/2]  tiled
    u8* xs = w4 + (size_t)O * (K / 2);            // [M, K/32] tiled
    u8* ws = xs + (size_t)M * (K / 32);           // [O, K/32] tiled

    const int ntk = K / 128;
    const int nkb = K / 1024;
    rotquant4_kernel<<<(M / 8) * nkb, 256, 0, stream>>>(x, x4, xs, K, ntk, nkb);
    rotquant4_kernel<<<(O / 8) * nkb, 256, 0, stream>>>(w, w4, ws, K, ntk, nkb);

    dim3 grid((M / 256) * (O / 256));     // 2048 blocks
    gemm4_bias<<<grid, 512, 0, stream>>>(x4, xs, w4, ws, bias, (float*)d_out,
                                         M, O, K);
}